// Round 1
// baseline (971.662 us; speedup 1.0000x reference)
//
#include <hip/hip_runtime.h>
#include <hip/hip_bf16.h>
#include <stdint.h>

typedef __hip_bfloat16 bf16;
typedef __attribute__((ext_vector_type(8))) short s16x8;
typedef __attribute__((ext_vector_type(4))) float f32x4;

#define DEV __device__ __forceinline__

static constexpr int B_ = 8, L_ = 1024, D_ = 512, H_ = 8, HD_ = 64, DFF_ = 2048;
static constexpr int MAXK_ = 50;
static constexpr size_t RES_ELEMS = (size_t)B_ * L_ * D_;   // 4,194,304

// ---------------- workspace layout (bytes) ----------------
static constexpr size_t SZ_BLD_BF = (size_t)B_ * L_ * D_ * 2;   // 8 MB
static constexpr size_t SZ_BLD_F  = (size_t)B_ * L_ * D_ * 4;   // 16 MB
static constexpr size_t O_XBF  = 0;
static constexpr size_t O_WQT  = O_XBF + SZ_BLD_BF;             // wq^T, wk^T, wv^T contiguous -> [1536][512]
static constexpr size_t O_WOT  = O_WQT + 3 * (size_t)D_ * D_ * 2;
static constexpr size_t O_GW   = O_WOT + (size_t)D_ * D_ * 2;
static constexpr size_t O_C1W  = O_GW + (size_t)D_ * D_ * 2;
static constexpr size_t O_C2W  = O_C1W + (size_t)DFF_ * D_ * 2;
static constexpr size_t O_CB   = O_C2W + (size_t)D_ * DFF_ * 2; // concat qkv bias [1536] f32
static constexpr size_t O_QKV  = O_CB + 8192;                   // [8192][1536] bf16 = 24 MB
static constexpr size_t O_VT   = O_QKV + (size_t)B_ * L_ * 3 * D_ * 2; // [B][H][64][1024] bf16 = 8 MB
static constexpr size_t O_OATT = O_VT + SZ_BLD_BF;              // attn out bf16 [8192][512]
static constexpr size_t O_X1   = O_OATT + SZ_BLD_BF;            // f32, also reused as x2
static constexpr size_t O_S1F  = O_X1 + SZ_BLD_F;
static constexpr size_t O_S1B  = O_S1F + SZ_BLD_F;
static constexpr size_t O_YG   = O_S1B + SZ_BLD_BF;
static constexpr size_t O_XG   = O_YG + SZ_BLD_BF;              // [8][512] f32
static constexpr size_t O_KK   = O_XG + 8 * 512 * 4;
static constexpr size_t O_WSM  = O_KK + 256;                    // [8][64] f32
static constexpr size_t O_Y1   = O_QKV;                         // alias: 32 MB over QKV+VT (dead by FFN)

// ---------------- small kernels ----------------
__global__ void k_cast_bf16(const float* __restrict__ in, bf16* __restrict__ out, int n8) {
  int i = blockIdx.x * blockDim.x + threadIdx.x;
  if (i >= n8) return;
  const float4* p = (const float4*)in;
  float4 a = p[2 * (size_t)i], b = p[2 * (size_t)i + 1];
  union { bf16 h[8]; uint4 v; } u;
  u.h[0] = __float2bfloat16(a.x); u.h[1] = __float2bfloat16(a.y);
  u.h[2] = __float2bfloat16(a.z); u.h[3] = __float2bfloat16(a.w);
  u.h[4] = __float2bfloat16(b.x); u.h[5] = __float2bfloat16(b.y);
  u.h[6] = __float2bfloat16(b.z); u.h[7] = __float2bfloat16(b.w);
  *(uint4*)(out + 8 * (size_t)i) = u.v;
}

// out[n][k] = bf16(in[k][n]); in is rows x cols (k x n)
__global__ void k_transpose_cast(const float* __restrict__ in, bf16* __restrict__ out, int rows, int cols) {
  __shared__ float tile[64][65];
  int t = threadIdx.x, tx = t & 63, ty = t >> 6;
  int r0 = blockIdx.y * 64, c0 = blockIdx.x * 64;
  #pragma unroll
  for (int r = ty; r < 64; r += 4) tile[r][tx] = in[(size_t)(r0 + r) * cols + c0 + tx];
  __syncthreads();
  #pragma unroll
  for (int r = ty; r < 64; r += 4) out[(size_t)(c0 + r) * rows + r0 + tx] = __float2bfloat16(tile[tx][r]);
}

__global__ void k_concat_bias(const float* __restrict__ a, const float* __restrict__ b,
                              const float* __restrict__ c, float* __restrict__ o) {
  int i = blockIdx.x * 256 + threadIdx.x;
  if (i >= 1536) return;
  o[i] = (i < 512) ? a[i] : (i < 1024 ? b[i - 512] : c[i - 1024]);
}

// vT[b][h][e][l] = v[b,l,h,e]; v points at the v-columns of qkv buffer (ld elements per row)
__global__ void k_transpose_v(const bf16* __restrict__ v, bf16* __restrict__ vT, int ld) {
  __shared__ bf16 tile[64][72];
  int t = threadIdx.x, tx = t & 63, ty = t >> 6;
  int bh = blockIdx.y; int b = bh >> 3, h = bh & 7;
  int l0 = blockIdx.x * 64;
  #pragma unroll
  for (int r = ty; r < 64; r += 4) tile[r][tx] = v[((size_t)b * L_ + l0 + r) * ld + h * HD_ + tx];
  __syncthreads();
  #pragma unroll
  for (int r = ty; r < 64; r += 4) vT[((size_t)bh * HD_ + r) * L_ + l0 + tx] = tile[tx][r];
}

// ---------------- GEMM (B^T layout), bf16 MFMA 16x16x32 ----------------
enum { EPI_QKV = 0, EPI_SCORES = 1, EPI_PV = 2, EPI_OPROJ = 3, EPI_GATE = 4, EPI_RELU = 5, EPI_CONV2 = 6 };

DEV void gload16(const void* g, void* l) {
  __builtin_amdgcn_global_load_lds((const __attribute__((address_space(1))) void*)g,
                                   (__attribute__((address_space(3))) void*)l, 16, 0, 0);
}

template<int BM, int BN, int BK, int WGM, int WGN, int EPI, bool AF32>
__global__ __launch_bounds__(WGM * WGN * 64)
void k_gemm(const void* __restrict__ Av, const bf16* __restrict__ Bp,
            float* __restrict__ Cf, bf16* __restrict__ Cb,
            int lda, int ldb, int ldc, int K,
            long ab_b, long ab_h, long bb_b, long bb_h, long cb_b, long cb_h,
            const float* __restrict__ bias, const float* __restrict__ resid,
            const float* __restrict__ scaleptr, float alpha)
{
  constexpr int NT = WGM * WGN * 64;
  constexpr int ROWB = BK * 2;          // LDS bytes per row
  constexpr int SLOTS = ROWB / 16;      // 16B slots per row
  constexpr int WTM = BM / WGM, WTN = BN / WGN;
  constexpr int FM = WTM / 16, FN = WTN / 16;
  constexpr int ACALLS = BM * BK * 2 / (NT * 16);
  constexpr int BCALLS = BN * BK * 2 / (NT * 16);

  __shared__ __align__(16) bf16 lds[(BM + BN) * BK];
  bf16* ldsA = lds;
  bf16* ldsB = lds + BM * BK;

  const int tid = threadIdx.x;
  const int z = blockIdx.z, zb = z >> 3, zh = z & 7;
  const int row0 = blockIdx.y * BM, col0 = blockIdx.x * BN;
  const int lane = tid & 63, wave = tid >> 6;
  const int wm = wave / WGN, wn = wave % WGN;
  const size_t aoff = (size_t)(zb * ab_b + zh * ab_h);
  const bf16*  Ab  = (const bf16*)Av + aoff;
  const float* A32 = (const float*)Av + aoff;
  const bf16*  Bb  = Bp + (size_t)(zb * bb_b + zh * bb_h);
  const size_t coff = (size_t)(zb * cb_b + zh * cb_h);

  f32x4 acc[FM][FN] = {};

  for (int kt = 0; kt < K; kt += BK) {
    #pragma unroll
    for (int c = 0; c < ACALLS; ++c) {
      int q = (c * NT + tid) * 16;
      int r = q / ROWB, s = (q % ROWB) >> 4;
      int sl = s ^ (r & (SLOTS - 1));
      if constexpr (AF32) {
        const float* g = A32 + (size_t)(row0 + r) * lda + kt + sl * 8;
        float4 f0 = *(const float4*)g;
        float4 f1 = *(const float4*)(g + 4);
        union { bf16 h[8]; uint4 v4; } u;
        u.h[0] = __float2bfloat16(f0.x); u.h[1] = __float2bfloat16(f0.y);
        u.h[2] = __float2bfloat16(f0.z); u.h[3] = __float2bfloat16(f0.w);
        u.h[4] = __float2bfloat16(f1.x); u.h[5] = __float2bfloat16(f1.y);
        u.h[6] = __float2bfloat16(f1.z); u.h[7] = __float2bfloat16(f1.w);
        *(uint4*)((char*)ldsA + q) = u.v4;
      } else {
        gload16(Ab + (size_t)(row0 + r) * lda + kt + sl * 8, (char*)ldsA + q);
      }
    }
    #pragma unroll
    for (int c = 0; c < BCALLS; ++c) {
      int q = (c * NT + tid) * 16;
      int r = q / ROWB, s = (q % ROWB) >> 4;
      int sl = s ^ (r & (SLOTS - 1));
      gload16(Bb + (size_t)(col0 + r) * ldb + kt + sl * 8, (char*)ldsB + q);
    }
    __syncthreads();
    #pragma unroll
    for (int ks = 0; ks < BK / 32; ++ks) {
      s16x8 af[FM], bfr[FN];
      #pragma unroll
      for (int i = 0; i < FM; ++i) {
        int r = wm * WTM + i * 16 + (lane & 15);
        int s = ks * 4 + (lane >> 4);
        af[i] = *(const s16x8*)((const char*)ldsA + r * ROWB + ((s ^ (r & (SLOTS - 1))) << 4));
      }
      #pragma unroll
      for (int j = 0; j < FN; ++j) {
        int r = wn * WTN + j * 16 + (lane & 15);
        int s = ks * 4 + (lane >> 4);
        bfr[j] = *(const s16x8*)((const char*)ldsB + r * ROWB + ((s ^ (r & (SLOTS - 1))) << 4));
      }
      #pragma unroll
      for (int i = 0; i < FM; ++i)
        #pragma unroll
        for (int j = 0; j < FN; ++j)
          acc[i][j] = __builtin_amdgcn_mfma_f32_16x16x32_bf16(af[i], bfr[j], acc[i][j], 0, 0, 0);
    }
    __syncthreads();
  }

  #pragma unroll
  for (int i = 0; i < FM; ++i) {
    #pragma unroll
    for (int j = 0; j < FN; ++j) {
      #pragma unroll
      for (int r = 0; r < 4; ++r) {
        int m = row0 + wm * WTM + i * 16 + (lane >> 4) * 4 + r;
        int n = col0 + wn * WTN + j * 16 + (lane & 15);
        float v = acc[i][j][r];
        size_t idx = coff + (size_t)m * ldc + n;
        if constexpr (EPI == EPI_QKV) {
          Cb[idx] = __float2bfloat16(v + bias[n]);
        } else if constexpr (EPI == EPI_SCORES) {
          Cf[idx] = v * alpha;
        } else if constexpr (EPI == EPI_PV) {
          Cb[idx] = __float2bfloat16(v);
        } else if constexpr (EPI == EPI_OPROJ) {
          size_t ri = (size_t)m * ldc + n;
          Cf[idx] = resid[ri] + scaleptr[0] * (v + bias[n]);
        } else if constexpr (EPI == EPI_GATE) {
          float sg = 1.f / (1.f + __expf(-(v + bias[n])));
          size_t ri = (size_t)m * ldc + n;
          Cb[idx] = __float2bfloat16(resid[ri] * sg);
        } else if constexpr (EPI == EPI_RELU) {
          Cb[idx] = __float2bfloat16(fmaxf(v, 0.f));
        } else { // EPI_CONV2
          size_t ri = (size_t)m * ldc + n;
          Cf[idx] = resid[ri] + scaleptr[0] * v;
        }
      }
    }
  }
}

// ---------------- softmax over rows of 1024 (in-place, fp32) ----------------
__global__ void k_softmax(float* __restrict__ p) {
  size_t row = blockIdx.x;
  int t = threadIdx.x;
  float4* pr = (float4*)(p + row * 1024);
  float4 v = pr[t];
  float m = fmaxf(fmaxf(v.x, v.y), fmaxf(v.z, v.w));
  #pragma unroll
  for (int o = 32; o; o >>= 1) m = fmaxf(m, __shfl_xor(m, o));
  __shared__ float redm[4], reds[4];
  if ((t & 63) == 0) redm[t >> 6] = m;
  __syncthreads();
  m = fmaxf(fmaxf(redm[0], redm[1]), fmaxf(redm[2], redm[3]));
  v.x = __expf(v.x - m); v.y = __expf(v.y - m);
  v.z = __expf(v.z - m); v.w = __expf(v.w - m);
  float s = v.x + v.y + v.z + v.w;
  #pragma unroll
  for (int o = 32; o; o >>= 1) s += __shfl_xor(s, o);
  if ((t & 63) == 0) reds[t >> 6] = s;
  __syncthreads();
  s = reds[0] + reds[1] + reds[2] + reds[3];
  float inv = 1.f / s;
  v.x *= inv; v.y *= inv; v.z *= inv; v.w *= inv;
  pr[t] = v;
}

// ---------------- decomp helpers (exact fp32) ----------------
__global__ void k_mean(const float* __restrict__ x, float* __restrict__ xg) {
  int b = blockIdx.y;
  int d = blockIdx.x * 256 + threadIdx.x;
  const float* p = x + (size_t)b * L_ * D_ + d;
  float s = 0.f;
  #pragma unroll 4
  for (int l = 0; l < L_; ++l) s += p[(size_t)l * D_];
  xg[b * D_ + d] = s * (1.f / 1024.f);
}

__global__ void k_pred(const float* __restrict__ xg, const float* __restrict__ tw,
                       const float* __restrict__ w1, const float* __restrict__ b1,
                       const float* __restrict__ w2, const float* __restrict__ b2,
                       int* __restrict__ kk, float* __restrict__ wout)
{
  int b = blockIdx.x, j = threadIdx.x;
  __shared__ float xs[512];
  __shared__ float red[4];
  xs[j] = xg[b * D_ + j];
  xs[j + 256] = xg[b * D_ + 256 + j];
  __syncthreads();
  float h = b1[j];
  for (int i = 0; i < 512; ++i) h += xs[i] * w1[i * 256 + j];
  h = fmaxf(h, 0.f);
  float part = h * w2[j];
  #pragma unroll
  for (int o = 32; o; o >>= 1) part += __shfl_xor(part, o);
  if ((j & 63) == 0) red[j >> 6] = part;
  __syncthreads();
  if (j == 0) {
    float s = red[0] + red[1] + red[2] + red[3] + b2[0];
    s = 1.f / (1.f + expf(-s));
    float kf = rintf(s * 45.f + 5.f);   // round-half-even like jnp.round
    int k = (int)kf;
    k = k < 5 ? 5 : (k > 50 ? 50 : k);
    kk[b] = k;
    float m = -3.4e38f;
    for (int i = 0; i < k; ++i) m = fmaxf(m, tw[i]);
    float sum = 0.f;
    float e[MAXK_];
    for (int i = 0; i < k; ++i) { e[i] = expf(tw[i] - m); sum += e[i]; }
    float inv = 1.f / sum;
    for (int i = 0; i < 64; ++i) wout[b * 64 + i] = (i < k) ? e[i] * inv : 0.f;
  }
}

template<bool BOUT>
__global__ void k_decomp(const float* __restrict__ x, const float* __restrict__ w,
                         const int* __restrict__ kk, float* __restrict__ sf,
                         bf16* __restrict__ sb)
{
  int b = blockIdx.y, t = blockIdx.x, dj = threadIdx.x;
  int k = kk[b], half = k >> 1;
  const float2* xb = (const float2*)(x + (size_t)b * L_ * D_);
  float ax = 0.f, ay = 0.f;
  for (int i = 0; i < k; ++i) {
    int idx = t - half + i;
    idx = idx < 0 ? 0 : (idx > L_ - 1 ? L_ - 1 : idx);
    float wi = w[b * 64 + i];
    float2 g = xb[(size_t)idx * (D_ / 2) + dj];
    ax += wi * g.x; ay += wi * g.y;
  }
  float2 c = xb[(size_t)t * (D_ / 2) + dj];
  float2 o; o.x = c.x - ax; o.y = c.y - ay;
  size_t oi = ((size_t)b * L_ + t) * (D_ / 2) + dj;
  ((float2*)sf)[oi] = o;
  if constexpr (BOUT) {
    union { bf16 h[2]; unsigned u; } u2;
    u2.h[0] = __float2bfloat16(o.x); u2.h[1] = __float2bfloat16(o.y);
    *(unsigned*)(sb + 2 * oi) = u2.u;
  }
}

// ---------------- launch ----------------
extern "C" void kernel_launch(void* const* d_in, const int* in_sizes, int n_in,
                              void* d_out, int out_size, void* d_ws, size_t ws_size,
                              hipStream_t stream)
{
  const float* x    = (const float*)d_in[0];
  const float* Wq   = (const float*)d_in[1];
  const float* bq   = (const float*)d_in[2];
  const float* Wk   = (const float*)d_in[3];
  const float* bk   = (const float*)d_in[4];
  const float* Wv   = (const float*)d_in[5];
  const float* bv   = (const float*)d_in[6];
  const float* Wo   = (const float*)d_in[7];
  const float* bo   = (const float*)d_in[8];
  const float* gw   = (const float*)d_in[9];
  const float* gb   = (const float*)d_in[10];
  const float* c1w  = (const float*)d_in[11];
  const float* c2w  = (const float*)d_in[12];
  const float* tw1  = (const float*)d_in[13];
  const float* k1w1 = (const float*)d_in[14];
  const float* k1b1 = (const float*)d_in[15];
  const float* k1w2 = (const float*)d_in[16];
  const float* k1b2 = (const float*)d_in[17];
  const float* tw2  = (const float*)d_in[18];
  const float* k2w1 = (const float*)d_in[19];
  const float* k2b1 = (const float*)d_in[20];
  const float* k2w2 = (const float*)d_in[21];
  const float* k2b2 = (const float*)d_in[22];
  const float* ascale = (const float*)d_in[23];
  const float* fscale = (const float*)d_in[24];

  char* ws = (char*)d_ws;
  bf16* xbf  = (bf16*)(ws + O_XBF);
  bf16* wqT  = (bf16*)(ws + O_WQT);          // [1536][512] combined q,k,v
  bf16* woT  = (bf16*)(ws + O_WOT);
  bf16* gwB  = (bf16*)(ws + O_GW);
  bf16* c1B  = (bf16*)(ws + O_C1W);
  bf16* c2B  = (bf16*)(ws + O_C2W);
  float* cb  = (float*)(ws + O_CB);
  bf16* qkv  = (bf16*)(ws + O_QKV);
  bf16* vT   = (bf16*)(ws + O_VT);
  bf16* oatt = (bf16*)(ws + O_OATT);
  float* x1  = (float*)(ws + O_X1);          // also x2
  float* s1f = (float*)(ws + O_S1F);
  bf16* s1b  = (bf16*)(ws + O_S1B);
  bf16* yg   = (bf16*)(ws + O_YG);
  bf16* y1   = (bf16*)(ws + O_Y1);
  float* xg  = (float*)(ws + O_XG);
  int*  kkb  = (int*)(ws + O_KK);
  float* wsm = (float*)(ws + O_WSM);

  float* res_out = (float*)d_out;
  float* attn = (float*)d_out + RES_ELEMS;

  // ---- casts / transposes ----
  k_cast_bf16<<<dim3(2048), 256, 0, stream>>>(x, xbf, B_ * L_ * D_ / 8);
  k_transpose_cast<<<dim3(8, 8), 256, 0, stream>>>(Wq, wqT, D_, D_);
  k_transpose_cast<<<dim3(8, 8), 256, 0, stream>>>(Wk, wqT + (size_t)D_ * D_, D_, D_);
  k_transpose_cast<<<dim3(8, 8), 256, 0, stream>>>(Wv, wqT + 2 * (size_t)D_ * D_, D_, D_);
  k_transpose_cast<<<dim3(8, 8), 256, 0, stream>>>(Wo, woT, D_, D_);
  k_cast_bf16<<<dim3(128), 256, 0, stream>>>(gw, gwB, D_ * D_ / 8);
  k_cast_bf16<<<dim3(512), 256, 0, stream>>>(c1w, c1B, DFF_ * D_ / 8);
  k_cast_bf16<<<dim3(512), 256, 0, stream>>>(c2w, c2B, D_ * DFF_ / 8);
  k_concat_bias<<<dim3(6), 256, 0, stream>>>(bq, bk, bv, cb);

  // ---- fused QKV: [8192,512] x [512,1536] -> qkv bf16 [8192][1536] ----
  k_gemm<128, 128, 64, 2, 2, EPI_QKV, false><<<dim3(12, 64, 1), 256, 0, stream>>>(
      xbf, wqT, nullptr, qkv, D_, D_, 3 * D_, D_,
      0, 0, 0, 0, 0, 0, cb, nullptr, nullptr, 1.f);

  // ---- v transpose: vT[b][h][e][l] ----
  k_transpose_v<<<dim3(16, 64), 256, 0, stream>>>(qkv + 2 * D_, vT, 3 * D_);

  // ---- scores: per (b,h)  q[1024,64] @ k^T -> attn (fp32, *1/8) ----
  k_gemm<128, 128, 64, 2, 2, EPI_SCORES, false><<<dim3(8, 8, 64), 256, 0, stream>>>(
      qkv, qkv + D_, attn, nullptr, 3 * D_, 3 * D_, L_, HD_,
      (long)L_ * 3 * D_, HD_, (long)L_ * 3 * D_, HD_, (long)H_ * L_ * L_, (long)L_ * L_,
      nullptr, nullptr, nullptr, 0.125f);

  // ---- softmax rows (in place in d_out) ----
  k_softmax<<<dim3(B_ * H_ * L_), 256, 0, stream>>>(attn);

  // ---- PV: per (b,h)  P[1024,1024](fp32->bf16 staged) @ v -> oatt bf16 [8192,512] ----
  k_gemm<128, 64, 64, 2, 2, EPI_PV, true><<<dim3(1, 8, 64), 256, 0, stream>>>(
      attn, vT, nullptr, oatt, L_, L_, D_, L_,
      (long)H_ * L_ * L_, (long)L_ * L_, (long)H_ * HD_ * L_, (long)HD_ * L_, (long)L_ * D_, HD_,
      nullptr, nullptr, nullptr, 1.f);

  // ---- out proj + residual: x1 = x + ascale*(oatt@Wo + bo) ----
  k_gemm<128, 128, 64, 2, 2, EPI_OPROJ, false><<<dim3(4, 64, 1), 256, 0, stream>>>(
      oatt, woT, x1, nullptr, D_, D_, D_, D_,
      0, 0, 0, 0, 0, 0, bo, x, ascale, 1.f);

  // ---- decomp 1 ----
  k_mean<<<dim3(2, 8), 256, 0, stream>>>(x1, xg);
  k_pred<<<dim3(8), 256, 0, stream>>>(xg, tw1, k1w1, k1b1, k1w2, k1b2, kkb, wsm);
  k_decomp<true><<<dim3(L_, B_), 256, 0, stream>>>(x1, wsm, kkb, s1f, s1b);

  // ---- FFN: gate, conv1+relu, conv2+residual ----
  k_gemm<128, 128, 64, 2, 2, EPI_GATE, false><<<dim3(4, 64, 1), 256, 0, stream>>>(
      s1b, gwB, nullptr, yg, D_, D_, D_, D_,
      0, 0, 0, 0, 0, 0, gb, s1f, nullptr, 1.f);
  k_gemm<128, 128, 64, 2, 2, EPI_RELU, false><<<dim3(16, 64, 1), 256, 0, stream>>>(
      yg, c1B, nullptr, y1, D_, D_, DFF_, D_,
      0, 0, 0, 0, 0, 0, nullptr, nullptr, nullptr, 1.f);
  k_gemm<128, 128, 64, 2, 2, EPI_CONV2, false><<<dim3(4, 64, 1), 256, 0, stream>>>(
      y1, c2B, x1, nullptr, DFF_, DFF_, D_, DFF_,
      0, 0, 0, 0, 0, 0, nullptr, s1f, fscale, 1.f);

  // ---- decomp 2 -> res ----
  k_mean<<<dim3(2, 8), 256, 0, stream>>>(x1, xg);
  k_pred<<<dim3(8), 256, 0, stream>>>(xg, tw2, k2w1, k2b1, k2w2, k2b2, kkb, wsm);
  k_decomp<false><<<dim3(L_, B_), 256, 0, stream>>>(x1, wsm, kkb, res_out, nullptr);

  (void)in_sizes; (void)n_in; (void)out_size; (void)ws_size;
}